// Round 1
// baseline (1830.937 us; speedup 1.0000x reference)
//
#include <hip/hip_runtime.h>

// Problem constants
constexpr int K = 1024;        // num codes
constexpr int D = 64;          // dim
constexpr int N = 131072;      // 32*4096 points
constexpr float INV_N = 1.0f / 131072.0f;
constexpr float INV_ELEMS = 1.0f / 8388608.0f;  // N*D

// Output layout (flat, return order, all read as float32)
constexpr size_t O_QST  = 0;          // [N*D] quantized_st
constexpr size_t O_LOSS = 8388608;    // [1]
constexpr size_t O_IDX  = 8388609;    // [N] indices (written as float)
constexpr size_t O_CBL  = 8519681;    // [1] codebook_loss
constexpr size_t O_CML  = 8519682;    // [1] commitment_loss
constexpr size_t O_PPL  = 8519683;    // [1] perplexity
constexpr size_t O_USG  = 8519684;    // [1024] usage
constexpr size_t O_SU   = 8520708;    // [1024] soft_usage

// Workspace layout (floats)
// [0..1023]    cn  (codebook norms)
// [1024..2047] counts accumulator
// [2048..3071] soft_usage accumulator (sum of probs over points)
// [3072]       sum of squared errors

// ---------------------------------------------------------------------------
// Kernel A: codebook norms. One wave per code, lane d handles dim d.
__global__ __launch_bounds__(64) void vq_norms(const float* __restrict__ cb,
                                               float* __restrict__ cn) {
  const int c = blockIdx.x;
  const int d = threadIdx.x;
  float v = cb[c * D + d];
  float s = v * v;
#pragma unroll
  for (int o = 32; o > 0; o >>= 1) s += __shfl_xor(s, o, 64);
  if (d == 0) cn[c] = s;
}

// ---------------------------------------------------------------------------
// Kernel B: main. One thread per point. Codebook accessed with wave-uniform
// addresses (scalar loads); two passes: (1) online softmax + argmin,
// (2) prob accumulation into per-wave LDS soft_usage rows.
__global__ __launch_bounds__(256) void vq_main(
    const float* __restrict__ z, const float* __restrict__ cb,
    const float* __restrict__ cn, float* __restrict__ counts,
    float* __restrict__ susum, float* __restrict__ sqerr,
    float* __restrict__ out) {
  __shared__ float su_l[4][K];  // one row per wave (16 KiB)

  const int tid  = threadIdx.x;
  const int lane = tid & 63;
  const int w    = tid >> 6;
  const int i    = blockIdx.x * 256 + tid;  // point id; grid covers N exactly

  for (int idx = tid; idx < 4 * K; idx += 256) ((float*)su_l)[idx] = 0.0f;
  __syncthreads();

  // Load this point's z into registers (64 floats) and its norm.
  const float4* z4 = (const float4*)(z + (size_t)i * D);
  float4 zv[16];
  float zn = 0.0f;
#pragma unroll
  for (int k = 0; k < 16; k++) {
    zv[k] = z4[k];
    zn += zv[k].x * zv[k].x + zv[k].y * zv[k].y + zv[k].z * zv[k].z +
          zv[k].w * zv[k].w;
  }

  const float4* cb4 = (const float4*)cb;

  // ---- Pass 1: online min-distance softmax state + argmin ----
  float bestD = 3.0e38f;  // current min distance (softmax max = -bestD)
  int bestI = 0;
  float Zs = 0.0f;        // sum of exp(bestD - dist)
  for (int j = 0; j < K; j++) {
    const float4* cj = cb4 + (size_t)j * 16;
    float dot0 = 0.0f, dot1 = 0.0f;
#pragma unroll
    for (int k = 0; k < 16; k += 2) {
      float4 a = cj[k];
      float4 b = cj[k + 1];
      dot0 += zv[k].x * a.x + zv[k].y * a.y + zv[k].z * a.z + zv[k].w * a.w;
      dot1 += zv[k + 1].x * b.x + zv[k + 1].y * b.y + zv[k + 1].z * b.z +
              zv[k + 1].w * b.w;
    }
    float dist = (zn - 2.0f * (dot0 + dot1)) + cn[j];
    bool lt = dist < bestD;            // strict: first occurrence wins ties
    float nm = lt ? dist : bestD;
    Zs = Zs * __expf(nm - bestD) + __expf(nm - dist);
    bestI = lt ? j : bestI;
    bestD = nm;
  }
  const float invZ = 1.0f / Zs;

  // ---- Pass 2: recompute distances, accumulate normalized probs ----
  for (int j = 0; j < K; j++) {
    const float4* cj = cb4 + (size_t)j * 16;
    float dot0 = 0.0f, dot1 = 0.0f;
#pragma unroll
    for (int k = 0; k < 16; k += 2) {
      float4 a = cj[k];
      float4 b = cj[k + 1];
      dot0 += zv[k].x * a.x + zv[k].y * a.y + zv[k].z * a.z + zv[k].w * a.w;
      dot1 += zv[k + 1].x * b.x + zv[k + 1].y * b.y + zv[k + 1].z * b.z +
              zv[k + 1].w * b.w;
    }
    float dist = (zn - 2.0f * (dot0 + dot1)) + cn[j];
    float p = __expf(bestD - dist) * invZ;
    // wave-reduce p (all lanes are at the same code j)
#pragma unroll
    for (int o = 32; o > 0; o >>= 1) p += __shfl_xor(p, o, 64);
    if (lane == 0) su_l[w][j] += p;
  }

  // ---- Epilogue: quantized_st, losses, indices, counts ----
  const float4* q4 = (const float4*)(cb + (size_t)bestI * D);
  float4* o4 = (float4*)(out + O_QST + (size_t)i * D);
  float s = 0.0f;
#pragma unroll
  for (int k = 0; k < 16; k++) {
    float4 q = q4[k];
    float dx = q.x - zv[k].x;
    float dy = q.y - zv[k].y;
    float dz = q.z - zv[k].z;
    float dw = q.w - zv[k].w;
    s += dx * dx + dy * dy + dz * dz + dw * dw;
    o4[k] = make_float4(zv[k].x + dx, zv[k].y + dy, zv[k].z + dz,
                        zv[k].w + dw);
  }
  out[O_IDX + (size_t)i] = (float)bestI;
  atomicAdd(&counts[bestI], 1.0f);

#pragma unroll
  for (int o = 32; o > 0; o >>= 1) s += __shfl_xor(s, o, 64);
  if (lane == 0) atomicAdd(sqerr, s);

  __syncthreads();
  for (int j = tid; j < K; j += 256) {
    float v = su_l[0][j] + su_l[1][j] + su_l[2][j] + su_l[3][j];
    atomicAdd(&susum[j], v);
  }
}

// ---------------------------------------------------------------------------
// Kernel C: finalize scalars + usage vectors. One block, 1024 threads.
__global__ __launch_bounds__(1024) void vq_final(
    const float* __restrict__ counts, const float* __restrict__ susum,
    const float* __restrict__ sqerr, float* __restrict__ out) {
  __shared__ float red[16];
  const int t = threadIdx.x;
  float cnt = counts[t];
  float usage = cnt * INV_N;  // counts.sum() == N exactly
  out[O_USG + t] = usage;
  out[O_SU + t] = susum[t] * INV_N;
  float term = usage * logf(usage + 1e-8f);
#pragma unroll
  for (int o = 32; o > 0; o >>= 1) term += __shfl_xor(term, o, 64);
  if ((t & 63) == 0) red[t >> 6] = term;
  __syncthreads();
  if (t < 16) {
    float v = red[t];
#pragma unroll
    for (int o = 8; o > 0; o >>= 1) v += __shfl_xor(v, o, 64);
    if (t == 0) {
      float ppl = __expf(-v);
      float S = sqerr[0];
      float cbl = S * INV_ELEMS;
      out[O_LOSS] = cbl + 0.25f * cbl;  // codebook + 0.25*commitment (equal)
      out[O_CBL] = cbl;
      out[O_CML] = cbl;
      out[O_PPL] = ppl;
    }
  }
}

// ---------------------------------------------------------------------------
extern "C" void kernel_launch(void* const* d_in, const int* in_sizes, int n_in,
                              void* d_out, int out_size, void* d_ws,
                              size_t ws_size, hipStream_t stream) {
  const float* z = (const float*)d_in[0];
  const float* cb = (const float*)d_in[1];
  float* ws = (float*)d_ws;
  float* cn = ws;
  float* counts = ws + 1024;
  float* susum = ws + 2048;
  float* sqerr = ws + 3072;
  float* out = (float*)d_out;

  // zero the accumulators (ws is poisoned before every timed call)
  hipMemsetAsync(counts, 0, (1024 + 1024 + 1) * sizeof(float), stream);

  vq_norms<<<K, 64, 0, stream>>>(cb, cn);
  vq_main<<<N / 256, 256, 0, stream>>>(z, cb, cn, counts, susum, sqerr, out);
  vq_final<<<1, 1024, 0, stream>>>(counts, susum, sqerr, out);
}

// Round 2
// 1368.118 us; speedup vs baseline: 1.3383x; 1.3383x over previous
//
#include <hip/hip_runtime.h>

constexpr int K = 1024;        // num codes
constexpr int D = 64;          // dim
constexpr int N = 131072;      // 32*4096 points
constexpr float INV_N = 1.0f / 131072.0f;
constexpr float INV_ELEMS = 1.0f / 8388608.0f;  // N*D

// Output layout (flat float32, return order)
constexpr size_t O_QST  = 0;          // [N*D] quantized_st
constexpr size_t O_LOSS = 8388608;    // [1]
constexpr size_t O_IDX  = 8388609;    // [N]
constexpr size_t O_CBL  = 8519681;    // [1]
constexpr size_t O_CML  = 8519682;    // [1]
constexpr size_t O_PPL  = 8519683;    // [1]
constexpr size_t O_USG  = 8519684;    // [1024]
constexpr size_t O_SU   = 8520708;    // [1024]

// Workspace (floats): [0,1024) cn | [1024,2048) counts | [2048,3072) susum
//                     | [3072,3328) sqp (spread sqerr partials)

// Per-point scratch lives INSIDE the point's 64-float qst slot until the
// epilogue overwrites it:  slot[q]=m_q  slot[4+q]=Z_q  slot[8+q]=bI_q
//                          slot[12]=M   slot[13]=1/Z   slot[14]=bestI

// ---------------------------------------------------------------------------
__global__ __launch_bounds__(64) void vq_norms(const float* __restrict__ cb,
                                               float* __restrict__ cn) {
  const int c = blockIdx.x;
  const int d = threadIdx.x;
  float v = cb[c * D + d];
  float s = v * v;
#pragma unroll
  for (int o = 32; o > 0; o >>= 1) s += __shfl_xor(s, o, 64);
  if (d == 0) cn[c] = s;
}

// ---------------------------------------------------------------------------
// Pass 1: thread = (point, code-quarter). Online min/Z/argmin over 256 codes.
// score = cn_j - 2*dot (zn dropped: argmin & softmax are shift-invariant).
__global__ __launch_bounds__(256) void vq_pass1(const float* __restrict__ z,
                                                const float* __restrict__ cb,
                                                const float* __restrict__ cn,
                                                float* __restrict__ out) {
  const int pb = blockIdx.x >> 2;
  const int q  = blockIdx.x & 3;
  const int i  = pb * 256 + threadIdx.x;

  const float4* z4 = (const float4*)(z + (size_t)i * D);
  float4 zv[16];
#pragma unroll
  for (int k = 0; k < 16; k++) zv[k] = z4[k];

  const float4* cb4 = (const float4*)cb + (size_t)(q * 256) * 16;
  const float* cnq = cn + q * 256;

  float bestS = 3.0e38f;
  int bestI = 0;
  float Zs = 0.0f;
  for (int j = 0; j < 256; j++) {
    const float4* cj = cb4 + (size_t)j * 16;
    float dot0 = 0.0f, dot1 = 0.0f;
#pragma unroll
    for (int k = 0; k < 16; k += 2) {
      float4 a = cj[k];
      float4 b = cj[k + 1];
      dot0 += zv[k].x * a.x + zv[k].y * a.y + zv[k].z * a.z + zv[k].w * a.w;
      dot1 += zv[k + 1].x * b.x + zv[k + 1].y * b.y + zv[k + 1].z * b.z +
              zv[k + 1].w * b.w;
    }
    float s = cnq[j] - 2.0f * (dot0 + dot1);
    bool lt = s < bestS;                 // strict: first occurrence wins
    float nm = lt ? s : bestS;
    Zs = Zs * __expf(nm - bestS) + __expf(nm - s);
    bestI = lt ? (q * 256 + j) : bestI;
    bestS = nm;
  }
  float* slot = out + (size_t)i * 64;
  slot[q] = bestS;
  slot[4 + q] = Zs;
  slot[8 + q] = (float)bestI;
}

// ---------------------------------------------------------------------------
// Combine quarters -> (M, 1/Z, bestI) per point, stored back into the slot.
__global__ __launch_bounds__(256) void vq_combine(float* __restrict__ out) {
  const int i = blockIdx.x * 256 + threadIdx.x;
  float* slot = out + (size_t)i * 64;
  float m0 = slot[0], m1 = slot[1], m2 = slot[2], m3 = slot[3];
  float bs = m0;
  float bi = slot[8];
  if (m1 < bs) { bs = m1; bi = slot[9]; }
  if (m2 < bs) { bs = m2; bi = slot[10]; }
  if (m3 < bs) { bs = m3; bi = slot[11]; }
  float Z = slot[4] * __expf(bs - m0) + slot[5] * __expf(bs - m1) +
            slot[6] * __expf(bs - m2) + slot[7] * __expf(bs - m3);
  slot[12] = bs;
  slot[13] = 1.0f / Z;
  slot[14] = bi;
}

// ---------------------------------------------------------------------------
// Pass 2 (code-major): lane = one code (row in 64 VGPRs), iterate 256 points
// with wave-uniform z loads; soft_usage accumulates in ONE register.
__global__ __launch_bounds__(256) void vq_soft(const float* __restrict__ z,
                                               const float* __restrict__ cb,
                                               const float* __restrict__ cn,
                                               const float* __restrict__ out,
                                               float* __restrict__ susum) {
  const int W = __builtin_amdgcn_readfirstlane(blockIdx.x * 4 +
                                               ((int)threadIdx.x >> 6));
  const int lane = threadIdx.x & 63;
  const int g = W & 15;    // code group
  const int c = W >> 4;    // point chunk (512 chunks of 256 points)
  const int j = g * 64 + lane;

  const float4* cj = (const float4*)(cb + (size_t)j * D);
  float4 cr[16];
#pragma unroll
  for (int k = 0; k < 16; k++) cr[k] = cj[k];
  const float cnj = cn[j];

  float su = 0.0f;
  const int i0 = c * 256;
  for (int p = 0; p < 256; p++) {
    const int i = i0 + p;  // wave-uniform
    const float2 mz = *(const float2*)(out + (size_t)i * 64 + 12);
    const float4* zp = (const float4*)(z + (size_t)i * 64);
    float dot0 = 0.0f, dot1 = 0.0f;
#pragma unroll
    for (int k = 0; k < 16; k += 2) {
      float4 a = zp[k];
      float4 b = zp[k + 1];
      dot0 += a.x * cr[k].x + a.y * cr[k].y + a.z * cr[k].z + a.w * cr[k].w;
      dot1 += b.x * cr[k + 1].x + b.y * cr[k + 1].y + b.z * cr[k + 1].z +
              b.w * cr[k + 1].w;
    }
    float s = cnj - 2.0f * (dot0 + dot1);
    su += __expf(mz.x - s) * mz.y;
  }
  atomicAdd(&susum[j], su);
}

// ---------------------------------------------------------------------------
// Epilogue: wave per point. Coalesced cb[bestI] row read; overwrites slot
// with quantized_st; counts/indices/sqerr.
__global__ __launch_bounds__(256) void vq_epi(const float* __restrict__ z,
                                              const float* __restrict__ cb,
                                              float* __restrict__ out,
                                              float* __restrict__ counts,
                                              float* __restrict__ sqp) {
  __shared__ float red[4];
  const int w = (int)threadIdx.x >> 6;
  const int i = __builtin_amdgcn_readfirstlane(blockIdx.x * 4 + w);
  const int lane = threadIdx.x & 63;
  float* slot = out + (size_t)i * 64;
  const int bI = (int)slot[14];  // uniform load, consumed before overwrite
  float qv = cb[(size_t)bI * 64 + lane];
  float zv = z[(size_t)i * 64 + lane];
  float o = zv + (qv - zv);      // match reference's fp ordering
  float e = qv - zv;
  float s = e * e;
#pragma unroll
  for (int off = 32; off > 0; off >>= 1) s += __shfl_xor(s, off, 64);
  slot[lane] = o;
  if (lane == 0) {
    out[O_IDX + (size_t)i] = (float)bI;
    atomicAdd(&counts[bI], 1.0f);
    red[w] = s;
  }
  __syncthreads();
  if (threadIdx.x == 0) {
    float v = red[0] + red[1] + red[2] + red[3];
    atomicAdd(&sqp[blockIdx.x & 255], v);
  }
}

// ---------------------------------------------------------------------------
__global__ __launch_bounds__(1024) void vq_final(
    const float* __restrict__ counts, const float* __restrict__ susum,
    const float* __restrict__ sqp, float* __restrict__ out) {
  __shared__ float red[16];
  __shared__ float red2[16];
  const int t = threadIdx.x;
  float cnt = counts[t];
  float usage = cnt * INV_N;  // counts.sum() == N exactly
  out[O_USG + t] = usage;
  out[O_SU + t] = susum[t] * INV_N;
  float term = usage * logf(usage + 1e-8f);
  float sq = (t < 256) ? sqp[t] : 0.0f;
#pragma unroll
  for (int o = 32; o > 0; o >>= 1) {
    term += __shfl_xor(term, o, 64);
    sq += __shfl_xor(sq, o, 64);
  }
  if ((t & 63) == 0) {
    red[t >> 6] = term;
    red2[t >> 6] = sq;
  }
  __syncthreads();
  if (t < 16) {
    float v = red[t];
    float s2 = red2[t];
#pragma unroll
    for (int o = 8; o > 0; o >>= 1) {
      v += __shfl_xor(v, o, 64);
      s2 += __shfl_xor(s2, o, 64);
    }
    if (t == 0) {
      float ppl = __expf(-v);
      float cbl = s2 * INV_ELEMS;
      out[O_LOSS] = cbl + 0.25f * cbl;
      out[O_CBL] = cbl;
      out[O_CML] = cbl;
      out[O_PPL] = ppl;
    }
  }
}

// ---------------------------------------------------------------------------
extern "C" void kernel_launch(void* const* d_in, const int* in_sizes, int n_in,
                              void* d_out, int out_size, void* d_ws,
                              size_t ws_size, hipStream_t stream) {
  const float* z = (const float*)d_in[0];
  const float* cb = (const float*)d_in[1];
  float* ws = (float*)d_ws;
  float* cn = ws;
  float* counts = ws + 1024;
  float* susum = ws + 2048;
  float* sqp = ws + 3072;
  float* out = (float*)d_out;

  hipMemsetAsync(counts, 0, (1024 + 1024 + 256) * sizeof(float), stream);

  vq_norms<<<K, 64, 0, stream>>>(cb, cn);
  vq_pass1<<<2048, 256, 0, stream>>>(z, cb, cn, out);
  vq_combine<<<N / 256, 256, 0, stream>>>(out);
  vq_soft<<<2048, 256, 0, stream>>>(z, cb, cn, out, susum);
  vq_epi<<<N / 4, 256, 0, stream>>>(z, cb, out, counts, sqp);
  vq_final<<<1, 1024, 0, stream>>>(counts, susum, sqp, out);
}

// Round 3
// 422.697 us; speedup vs baseline: 4.3316x; 3.2366x over previous
//
#include <hip/hip_runtime.h>

constexpr int K = 1024;        // num codes
constexpr int D = 64;          // dim
constexpr int N = 131072;      // 32*4096 points
constexpr float INV_N = 1.0f / 131072.0f;
constexpr float INV_ELEMS = 1.0f / 8388608.0f;  // N*D
constexpr float DELTA = 0.005f;  // refinement margin (>=10x approx err bound)

// Output layout (flat float32, return order)
constexpr size_t O_QST  = 0;          // [N*D] quantized_st
constexpr size_t O_LOSS = 8388608;    // [1]
constexpr size_t O_IDX  = 8388609;    // [N]
constexpr size_t O_CBL  = 8519681;    // [1]
constexpr size_t O_CML  = 8519682;    // [1]
constexpr size_t O_PPL  = 8519683;    // [1]
constexpr size_t O_USG  = 8519684;    // [1024]
constexpr size_t O_SU   = 8520708;    // [1024]

// Workspace (float offsets):
//  [0,1024)     cn      fp32 codebook norms
//  [1024,2048)  counts
//  [2048,3072)  susum
//  [3072,3328)  sqp     spread sqerr partials
//  [3328,4352)  cnP     packed bf16 split of cn (lo16=hi-part, hi16=lo-part)
//  [4352,37120) chA     bf16 hi split of codebook, MFMA-frag layout
//  [37120,69888) clA    bf16 lo split
// total ~280 KB

// Per-point scratch inside the qst slot until epilogue overwrites it:
//  slot[0] = ct = m - ln(Z)   slot[1] = margin (best2-best1, approx)
// approx argmin goes straight to O_IDX (refined by epilogue if needed).

typedef __attribute__((ext_vector_type(8))) short bf16x8;
typedef __attribute__((ext_vector_type(16))) float f32x16;

__device__ inline unsigned short f2bf(float f) {  // RTNE fp32->bf16
  unsigned u = __float_as_uint(f);
  return (unsigned short)((u + 0x7FFF + ((u >> 16) & 1)) >> 16);
}
__device__ inline float bf2f(unsigned short h) {
  return __uint_as_float(((unsigned)h) << 16);
}

// ---------------------------------------------------------------------------
__global__ __launch_bounds__(64) void vq_norms(const float* __restrict__ cb,
                                               float* __restrict__ cn) {
  const int c = blockIdx.x;
  const int d = threadIdx.x;
  float v = cb[c * D + d];
  float s = v * v;
#pragma unroll
  for (int o = 32; o > 0; o >>= 1) s += __shfl_xor(s, o, 64);
  if (d == 0) cn[c] = s;
}

// ---------------------------------------------------------------------------
// Split codebook into bf16 hi/lo in MFMA fragment layout:
// frag element for (code c, dim d): tile=c>>5, ks=d>>4, lane=((d>>3)&1)*32+(c&31),
// j=d&7 -> offset ((tile*4+ks)*64+lane)*8+j.  Also pack cn splits.
__global__ __launch_bounds__(256) void vq_prep(const float* __restrict__ cb,
                                               const float* __restrict__ cn,
                                               short* __restrict__ chA,
                                               short* __restrict__ clA,
                                               unsigned* __restrict__ cnP) {
  const int gid = blockIdx.x * 256 + threadIdx.x;  // 65536 = 1024*64
  const int c = gid >> 6, d = gid & 63;
  float v = cb[gid];
  unsigned short h = f2bf(v);
  unsigned short l = f2bf(v - bf2f(h));
  const int tile = c >> 5, ks = d >> 4, hf = (d >> 3) & 1, j = d & 7;
  const int lane = hf * 32 + (c & 31);
  const size_t off = ((size_t)((tile * 4 + ks) * 64 + lane)) * 8 + j;
  chA[off] = (short)h;
  clA[off] = (short)l;
  if (d == 0) {
    float s = cn[c];
    unsigned short sh = f2bf(s);
    unsigned short sl = f2bf(s - bf2f(sh));
    cnP[c] = (unsigned)sh | ((unsigned)sl << 16);
  }
}

// ---------------------------------------------------------------------------
// Pass 1: wave = 32 points x all 1024 codes via split-bf16 MFMA.
// acc = cn - 2*z.c (cn folded via extra K-step). Online m/Z/argmin/best2.
__global__ __launch_bounds__(256) void vq_p1(const float* __restrict__ z,
                                             const short* __restrict__ chA,
                                             const short* __restrict__ clA,
                                             const unsigned* __restrict__ cnP,
                                             float* __restrict__ out) {
  const int lane = threadIdx.x & 63;
  const int W = blockIdx.x * 4 + (threadIdx.x >> 6);
  const int i0 = W * 32;
  const int col = lane & 31;
  const int hf = lane >> 5;

  // resident point B-frags: -2*z, split hi/lo.  B[k][n]: n=lane&31, k=hf*8+j
  bf16x8 zh[4], zl[4];
  const float* zr = z + (size_t)(i0 + col) * 64 + hf * 8;
#pragma unroll
  for (int ks = 0; ks < 4; ks++) {
    float4 a = *(const float4*)(zr + ks * 16);
    float4 b = *(const float4*)(zr + ks * 16 + 4);
    float vv[8] = {a.x, a.y, a.z, a.w, b.x, b.y, b.z, b.w};
#pragma unroll
    for (int j = 0; j < 8; j++) {
      float vm = -2.0f * vv[j];
      unsigned short h = f2bf(vm);
      zh[ks][j] = (short)h;
      zl[ks][j] = (short)f2bf(vm - bf2f(h));
    }
  }
  const short ONE = (short)0x3F80;
  bf16x8 B5;
#pragma unroll
  for (int j = 0; j < 8; j++) B5[j] = 0;
  if (hf == 0) { B5[0] = ONE; B5[1] = ONE; }

  float m = 3.0e38f, Z = 0.0f, b1 = 3.0e38f, b2 = 3.0e38f;
  int bi = 0;

  for (int t = 0; t < 32; t++) {
    unsigned cp = cnP[t * 32 + col];
    bf16x8 A5;
#pragma unroll
    for (int j = 0; j < 8; j++) A5[j] = 0;
    if (hf == 0) { A5[0] = (short)(cp & 0xffff); A5[1] = (short)(cp >> 16); }
    f32x16 acc0, acc1;
#pragma unroll
    for (int r = 0; r < 16; r++) { acc0[r] = 0.0f; acc1[r] = 0.0f; }
    acc0 = __builtin_amdgcn_mfma_f32_32x32x16_bf16(A5, B5, acc0, 0, 0, 0);
    const short* ch = chA + ((size_t)(t * 4) * 64 + lane) * 8;
    const short* cl = clA + ((size_t)(t * 4) * 64 + lane) * 8;
#pragma unroll
    for (int ks = 0; ks < 4; ks++) {
      bf16x8 Ah = *(const bf16x8*)(ch + ks * 512);
      bf16x8 Al = *(const bf16x8*)(cl + ks * 512);
      acc0 = __builtin_amdgcn_mfma_f32_32x32x16_bf16(Ah, zh[ks], acc0, 0, 0, 0);
      acc1 = __builtin_amdgcn_mfma_f32_32x32x16_bf16(Ah, zl[ks], acc1, 0, 0, 0);
      acc1 = __builtin_amdgcn_mfma_f32_32x32x16_bf16(Al, zh[ks], acc1, 0, 0, 0);
    }
    float s[16];
#pragma unroll
    for (int r = 0; r < 16; r++) s[r] = acc0[r] + acc1[r];
    float cm = s[0];
#pragma unroll
    for (int r = 1; r < 16; r++) cm = fminf(cm, s[r]);
    float newm = fminf(m, cm);
    float zs = 0.0f;
#pragma unroll
    for (int r = 0; r < 16; r++) zs += __expf(newm - s[r]);
    Z = Z * __expf(newm - m) + zs;
    m = newm;
#pragma unroll
    for (int r = 0; r < 16; r++) {
      int code = t * 32 + (r & 3) + 8 * (r >> 2) + 4 * hf;
      bool lt = s[r] < b1;
      b2 = fminf(b2, fmaxf(s[r], b1));
      b1 = lt ? s[r] : b1;
      bi = lt ? code : bi;
    }
  }
  // merge the two half-wave partials (rows split by lane>>5)
  float m2 = __shfl_xor(m, 32, 64);
  float Z2 = __shfl_xor(Z, 32, 64);
  float b1o = __shfl_xor(b1, 32, 64);
  float b2o = __shfl_xor(b2, 32, 64);
  int bio = __shfl_xor(bi, 32, 64);
  float M = fminf(m, m2);
  float Zt = Z * __expf(M - m) + Z2 * __expf(M - m2);
  bool take = (b1o < b1) || (b1o == b1 && bio < bi);
  float g1 = fminf(b1, b1o);
  float g2 = fminf(fmaxf(b1, b1o), fminf(b2, b2o));
  int big = take ? bio : bi;
  if (hf == 0) {
    float* slot = out + O_QST + (size_t)(i0 + col) * 64;
    slot[0] = M - __logf(Zt);
    slot[1] = g2 - g1;
    out[O_IDX + (size_t)(i0 + col)] = (float)big;
  }
}

// ---------------------------------------------------------------------------
// Pass 2: wave = 32 resident codes, iterate point tiles.
// acc = m - s - lnZ directly (cn and ct=m-lnZ folded); su += exp(acc).
__global__ __launch_bounds__(256) void vq_p2(const float* __restrict__ z,
                                             const short* __restrict__ chA,
                                             const short* __restrict__ clA,
                                             const unsigned* __restrict__ cnP,
                                             const float* __restrict__ out,
                                             float* __restrict__ susum) {
  const int lane = threadIdx.x & 63;
  const int W = blockIdx.x * 4 + (threadIdx.x >> 6);
  const int g = W & 31;    // code tile
  const int pg = W >> 5;   // point group (1024 points)
  const int col = lane & 31;
  const int hf = lane >> 5;

  bf16x8 Bh[4], Bl[4];
  const short* ch = chA + ((size_t)(g * 4) * 64 + lane) * 8;
  const short* cl = clA + ((size_t)(g * 4) * 64 + lane) * 8;
#pragma unroll
  for (int ks = 0; ks < 4; ks++) {
    Bh[ks] = *(const bf16x8*)(ch + ks * 512);
    Bl[ks] = *(const bf16x8*)(cl + ks * 512);
  }
  const short ONE = (short)0x3F80, NEG1 = (short)0xBF80;
  unsigned cp = cnP[g * 32 + col];
  bf16x8 B5;
#pragma unroll
  for (int j = 0; j < 8; j++) B5[j] = 0;
  if (hf == 0) {
    B5[0] = (short)(cp & 0xffff);
    B5[1] = (short)(cp >> 16);
    B5[2] = ONE;
    B5[3] = ONE;
  }

  float su = 0.0f;
  for (int pt = 0; pt < 32; pt++) {
    const int i0 = pg * 1024 + pt * 32;
    const float* zr = z + (size_t)(i0 + col) * 64 + hf * 8;
    bf16x8 Ah[4], Al[4];
#pragma unroll
    for (int ks = 0; ks < 4; ks++) {
      float4 a = *(const float4*)(zr + ks * 16);
      float4 b = *(const float4*)(zr + ks * 16 + 4);
      float vv[8] = {a.x, a.y, a.z, a.w, b.x, b.y, b.z, b.w};
#pragma unroll
      for (int j = 0; j < 8; j++) {
        float vm = 2.0f * vv[j];
        unsigned short h = f2bf(vm);
        Ah[ks][j] = (short)h;
        Al[ks][j] = (short)f2bf(vm - bf2f(h));
      }
    }
    float ct = out[O_QST + (size_t)(i0 + col) * 64];  // m - lnZ
    unsigned short cth = f2bf(ct);
    unsigned short ctl = f2bf(ct - bf2f(cth));
    bf16x8 A5;
#pragma unroll
    for (int j = 0; j < 8; j++) A5[j] = 0;
    if (hf == 0) {
      A5[0] = NEG1; A5[1] = NEG1;
      A5[2] = (short)cth; A5[3] = (short)ctl;
    }
    f32x16 acc0, acc1;
#pragma unroll
    for (int r = 0; r < 16; r++) { acc0[r] = 0.0f; acc1[r] = 0.0f; }
    acc0 = __builtin_amdgcn_mfma_f32_32x32x16_bf16(A5, B5, acc0, 0, 0, 0);
#pragma unroll
    for (int ks = 0; ks < 4; ks++) {
      acc0 = __builtin_amdgcn_mfma_f32_32x32x16_bf16(Ah[ks], Bh[ks], acc0, 0, 0, 0);
      acc1 = __builtin_amdgcn_mfma_f32_32x32x16_bf16(Ah[ks], Bl[ks], acc1, 0, 0, 0);
      acc1 = __builtin_amdgcn_mfma_f32_32x32x16_bf16(Al[ks], Bh[ks], acc1, 0, 0, 0);
    }
#pragma unroll
    for (int r = 0; r < 16; r++) su += __expf(acc0[r] + acc1[r]);
  }
  su += __shfl_xor(su, 32, 64);
  if (hf == 0) atomicAdd(&susum[g * 32 + col], su);
}

// ---------------------------------------------------------------------------
// Epilogue: wave per point. Exact fp32 argmin refinement for small-margin
// points, then quantized_st / counts / indices / sqerr.
__global__ __launch_bounds__(256) void vq_epi(const float* __restrict__ z,
                                              const float* __restrict__ cb,
                                              const float* __restrict__ cn,
                                              float* __restrict__ out,
                                              float* __restrict__ counts,
                                              float* __restrict__ sqp) {
  __shared__ float red[4];
  const int wv = threadIdx.x >> 6;
  const int i = blockIdx.x * 4 + wv;
  const int lane = threadIdx.x & 63;
  float* slot = out + O_QST + (size_t)i * 64;
  int bI = (int)out[O_IDX + (size_t)i];
  const float margin = slot[1];  // wave-uniform

  if (margin < DELTA) {
    // exact fp32 re-scan of all 1024 codes for this point
    const float4* zi4 = (const float4*)(z + (size_t)i * 64);
    float4 zq[16];
#pragma unroll
    for (int k = 0; k < 16; k++) zq[k] = zi4[k];
    float best = 3.0e38f;
    int bidx = 0;
    for (int cc = 0; cc < 16; cc++) {
      int c = cc * 64 + lane;  // ascending per lane
      const float4* cr = (const float4*)(cb + (size_t)c * 64);
      float dot0 = 0.0f, dot1 = 0.0f;
#pragma unroll
      for (int k = 0; k < 16; k += 2) {
        float4 a = cr[k];
        float4 b = cr[k + 1];
        dot0 += zq[k].x * a.x + zq[k].y * a.y + zq[k].z * a.z + zq[k].w * a.w;
        dot1 += zq[k + 1].x * b.x + zq[k + 1].y * b.y + zq[k + 1].z * b.z +
                zq[k + 1].w * b.w;
      }
      float s = cn[c] - 2.0f * (dot0 + dot1);
      if (s < best) { best = s; bidx = c; }
    }
#pragma unroll
    for (int o = 32; o > 0; o >>= 1) {
      float ob = __shfl_xor(best, o, 64);
      int oi = __shfl_xor(bidx, o, 64);
      if (ob < best || (ob == best && oi < bidx)) { best = ob; bidx = oi; }
    }
    bI = bidx;
    if (lane == 0) out[O_IDX + (size_t)i] = (float)bI;
  }

  float qv = cb[(size_t)bI * 64 + lane];
  float zv = z[(size_t)i * 64 + lane];
  float o = zv + (qv - zv);
  float e = qv - zv;
  float s = e * e;
#pragma unroll
  for (int off = 32; off > 0; off >>= 1) s += __shfl_xor(s, off, 64);
  slot[lane] = o;
  if (lane == 0) {
    atomicAdd(&counts[bI], 1.0f);
    red[wv] = s;
  }
  __syncthreads();
  if (threadIdx.x == 0) {
    float v = red[0] + red[1] + red[2] + red[3];
    atomicAdd(&sqp[blockIdx.x & 255], v);
  }
}

// ---------------------------------------------------------------------------
__global__ __launch_bounds__(1024) void vq_final(
    const float* __restrict__ counts, const float* __restrict__ susum,
    const float* __restrict__ sqp, float* __restrict__ out) {
  __shared__ float red[16];
  __shared__ float red2[16];
  const int t = threadIdx.x;
  float cnt = counts[t];
  float usage = cnt * INV_N;  // counts.sum() == N exactly
  out[O_USG + t] = usage;
  out[O_SU + t] = susum[t] * INV_N;
  float term = usage * logf(usage + 1e-8f);
  float sq = (t < 256) ? sqp[t] : 0.0f;
#pragma unroll
  for (int o = 32; o > 0; o >>= 1) {
    term += __shfl_xor(term, o, 64);
    sq += __shfl_xor(sq, o, 64);
  }
  if ((t & 63) == 0) {
    red[t >> 6] = term;
    red2[t >> 6] = sq;
  }
  __syncthreads();
  if (t < 16) {
    float v = red[t];
    float s2 = red2[t];
#pragma unroll
    for (int o = 8; o > 0; o >>= 1) {
      v += __shfl_xor(v, o, 64);
      s2 += __shfl_xor(s2, o, 64);
    }
    if (t == 0) {
      float ppl = __expf(-v);
      float cbl = s2 * INV_ELEMS;
      out[O_LOSS] = cbl + 0.25f * cbl;
      out[O_CBL] = cbl;
      out[O_CML] = cbl;
      out[O_PPL] = ppl;
    }
  }
}

// ---------------------------------------------------------------------------
extern "C" void kernel_launch(void* const* d_in, const int* in_sizes, int n_in,
                              void* d_out, int out_size, void* d_ws,
                              size_t ws_size, hipStream_t stream) {
  const float* z = (const float*)d_in[0];
  const float* cb = (const float*)d_in[1];
  float* ws = (float*)d_ws;
  float* cn = ws;
  float* counts = ws + 1024;
  float* susum = ws + 2048;
  float* sqp = ws + 3072;
  unsigned* cnP = (unsigned*)(ws + 3328);
  short* chA = (short*)(ws + 4352);
  short* clA = (short*)(ws + 37120);
  float* out = (float*)d_out;

  hipMemsetAsync(counts, 0, (1024 + 1024 + 256) * sizeof(float), stream);

  vq_norms<<<K, 64, 0, stream>>>(cb, cn);
  vq_prep<<<256, 256, 0, stream>>>(cb, cn, chA, clA, cnP);
  vq_p1<<<1024, 256, 0, stream>>>(z, chA, clA, cnP, out);
  vq_p2<<<1024, 256, 0, stream>>>(z, chA, clA, cnP, out, susum);
  vq_epi<<<N / 4, 256, 0, stream>>>(z, cb, cn, out, counts, sqp);
  vq_final<<<1, 1024, 0, stream>>>(counts, susum, sqp, out);
}

// Round 4
// 356.749 us; speedup vs baseline: 5.1323x; 1.1849x over previous
//
#include <hip/hip_runtime.h>

constexpr int K = 1024;        // num codes
constexpr int D = 64;          // dim
constexpr int N = 131072;      // 32*4096 points
constexpr float INV_N = 1.0f / 131072.0f;
constexpr float INV_ELEMS = 1.0f / 8388608.0f;  // N*D
constexpr float LOG2E = 1.4426950408889634f;
constexpr float DELTA = 0.0072f;  // refine margin in log2e-scaled units

// Output layout (flat float32, return order)
constexpr size_t O_QST  = 0;          // [N*D] quantized_st
constexpr size_t O_LOSS = 8388608;    // [1]
constexpr size_t O_IDX  = 8388609;    // [N]
constexpr size_t O_CBL  = 8519681;    // [1]
constexpr size_t O_CML  = 8519682;    // [1]
constexpr size_t O_PPL  = 8519683;    // [1]
constexpr size_t O_USG  = 8519684;    // [1024]
constexpr size_t O_SU   = 8520708;    // [1024]

// Workspace (float offsets):
//  [0,1024)       cn    raw fp32 codebook norms (epilogue exact rescan)
//  [1024,2048)    counts
//  [2048,3072)    susum
//  [3072,3328)    sqp
//  [3328,4352)    cn2f  cn * log2e (fp32, acc-init)
//  [4352,37120)   chA   bf16 hi split of codebook*log2e, frag layout
//  [37120,69888)  clA   bf16 lo split
//  [69888,200960) ctA   per-point ct2 = m - log2(Z)
//  [200960,332032) mgA  per-point approx margin (scaled units)

// qst slots double as z-frag storage between p1 and epi:
// tile t (32 points): shorts base = t*4096; hi frag at (ks*64+lane)*8,
// lo frag at 2048 + (ks*64+lane)*8.  Element (point=lane&31,
// dim=16*ks+(lane>>5)*8+j) holds split of (-2*z).

typedef __attribute__((ext_vector_type(8))) short bf16x8;
typedef __attribute__((ext_vector_type(16))) float f32x16;

__device__ inline unsigned short f2bf(float f) {  // RTNE fp32->bf16
  unsigned u = __float_as_uint(f);
  return (unsigned short)((u + 0x7FFF + ((u >> 16) & 1)) >> 16);
}
__device__ inline float bf2f(unsigned short h) {
  return __uint_as_float(((unsigned)h) << 16);
}
__device__ inline bf16x8 negbf8(bf16x8 v) {  // flip sign of 8 packed bf16
  union { bf16x8 s; uint4 u; } x;
  x.s = v;
  x.u.x ^= 0x80008000u; x.u.y ^= 0x80008000u;
  x.u.z ^= 0x80008000u; x.u.w ^= 0x80008000u;
  return x.s;
}

// ---------------------------------------------------------------------------
__global__ __launch_bounds__(64) void vq_norms(const float* __restrict__ cb,
                                               float* __restrict__ cn) {
  const int c = blockIdx.x;
  const int d = threadIdx.x;
  float v = cb[c * D + d];
  float s = v * v;
#pragma unroll
  for (int o = 32; o > 0; o >>= 1) s += __shfl_xor(s, o, 64);
  if (d == 0) cn[c] = s;
}

// ---------------------------------------------------------------------------
// Codebook*log2e -> bf16 hi/lo frags + scaled norms.
__global__ __launch_bounds__(256) void vq_prep(const float* __restrict__ cb,
                                               const float* __restrict__ cn,
                                               short* __restrict__ chA,
                                               short* __restrict__ clA,
                                               float* __restrict__ cn2f) {
  const int gid = blockIdx.x * 256 + threadIdx.x;  // 65536
  const int c = gid >> 6, d = gid & 63;
  float v = cb[gid] * LOG2E;
  unsigned short h = f2bf(v);
  unsigned short l = f2bf(v - bf2f(h));
  const int tile = c >> 5, ks = d >> 4, hff = (d >> 3) & 1, j = d & 7;
  const int lane = hff * 32 + (c & 31);
  const size_t off = ((size_t)((tile * 4 + ks) * 64 + lane)) * 8 + j;
  chA[off] = (short)h;
  clA[off] = (short)l;
  if (d == 0) cn2f[c] = cn[c] * LOG2E;
}

// ---------------------------------------------------------------------------
// Pass 1: wave = 32 points x all 1024 codes. Splits z once (stores frags to
// qst slots for p2). acc0 initialized from fp32 cn2 loads (exact affine).
__global__ __launch_bounds__(256, 4) void vq_p1(
    const float* __restrict__ z, const short* __restrict__ chA,
    const short* __restrict__ clA, const float* __restrict__ cn2f,
    float* __restrict__ out, float* __restrict__ ctA,
    float* __restrict__ mgA) {
  const int lane = threadIdx.x & 63;
  const int W = blockIdx.x * 4 + (threadIdx.x >> 6);
  const int i0 = W * 32;
  const int col = lane & 31;
  const int hf = lane >> 5;

  // convert this tile's z -> -2z hi/lo frags (B-operand layout), store for p2
  bf16x8 zh[4], zl[4];
  const float* zr = z + (size_t)(i0 + col) * 64 + hf * 8;
#pragma unroll
  for (int ks = 0; ks < 4; ks++) {
    float4 a = *(const float4*)(zr + ks * 16);
    float4 b = *(const float4*)(zr + ks * 16 + 4);
    float vv[8] = {a.x, a.y, a.z, a.w, b.x, b.y, b.z, b.w};
#pragma unroll
    for (int j = 0; j < 8; j++) {
      float vm = -2.0f * vv[j];
      unsigned short h = f2bf(vm);
      zh[ks][j] = (short)h;
      zl[ks][j] = (short)f2bf(vm - bf2f(h));
    }
  }
  {
    short* base = (short*)out + (size_t)W * 4096;  // O_QST == 0
#pragma unroll
    for (int ks = 0; ks < 4; ks++) {
      *(bf16x8*)(base + (ks * 64 + lane) * 8) = zh[ks];
      *(bf16x8*)(base + 2048 + (ks * 64 + lane) * 8) = zl[ks];
    }
  }

  float m = 3.0e38f, Z = 0.0f, b1 = 3.0e38f, b2 = 3.0e38f;
  int bi = 0;

  for (int t = 0; t < 32; t++) {
    // acc0 init = cn2 of this tile's 16 row-codes (exact fp32 affine)
    float4 cniv[4];
#pragma unroll
    for (int q = 0; q < 4; q++)
      cniv[q] = *(const float4*)(cn2f + t * 32 + 8 * q + 4 * hf);
    f32x16 acc0, acc1;
#pragma unroll
    for (int r = 0; r < 16; r++) {
      acc0[r] = ((const float*)&cniv[r >> 2])[r & 3];
      acc1[r] = 0.0f;
    }
    const short* ch = chA + ((size_t)(t * 4) * 64 + lane) * 8;
    const short* cl = clA + ((size_t)(t * 4) * 64 + lane) * 8;
#pragma unroll
    for (int ks = 0; ks < 4; ks++) {
      bf16x8 Ah = *(const bf16x8*)(ch + ks * 512);
      bf16x8 Al = *(const bf16x8*)(cl + ks * 512);
      acc0 = __builtin_amdgcn_mfma_f32_32x32x16_bf16(Ah, zh[ks], acc0, 0, 0, 0);
      acc1 = __builtin_amdgcn_mfma_f32_32x32x16_bf16(Ah, zl[ks], acc1, 0, 0, 0);
      acc1 = __builtin_amdgcn_mfma_f32_32x32x16_bf16(Al, zh[ks], acc1, 0, 0, 0);
    }
    float s[16];
#pragma unroll
    for (int r = 0; r < 16; r++) s[r] = acc0[r] + acc1[r];
    float cm = s[0];
#pragma unroll
    for (int r = 1; r < 16; r++) cm = fminf(cm, s[r]);
    float newm = fminf(m, cm);
    float zs = 0.0f;
#pragma unroll
    for (int r = 0; r < 16; r++) zs += exp2f(newm - s[r]);
    Z = Z * exp2f(newm - m) + zs;
    m = newm;
#pragma unroll
    for (int r = 0; r < 16; r++) {
      int code = t * 32 + (r & 3) + 8 * (r >> 2) + 4 * hf;
      bool lt = s[r] < b1;
      b2 = fminf(b2, fmaxf(s[r], b1));
      b1 = lt ? s[r] : b1;
      bi = lt ? code : bi;
    }
  }
  // merge the two half-wave partials
  float m2 = __shfl_xor(m, 32, 64);
  float Z2 = __shfl_xor(Z, 32, 64);
  float b1o = __shfl_xor(b1, 32, 64);
  float b2o = __shfl_xor(b2, 32, 64);
  int bio = __shfl_xor(bi, 32, 64);
  float M = fminf(m, m2);
  float Zt = Z * exp2f(M - m) + Z2 * exp2f(M - m2);
  bool take = (b1o < b1) || (b1o == b1 && bio < bi);
  float g1 = fminf(b1, b1o);
  float g2 = fminf(fmaxf(b1, b1o), fminf(b2, b2o));
  int big = take ? bio : bi;
  if (hf == 0) {
    ctA[i0 + col] = M - __log2f(Zt);
    mgA[i0 + col] = g2 - g1;
    out[O_IDX + (size_t)(i0 + col)] = (float)big;
  }
}

// ---------------------------------------------------------------------------
// Pass 2: wave = 32 resident (negated) codes, streams prebuilt z A-frags.
// acc0 init = ct2_i - cn2_j (exact fp32); su += 2^acc.
__global__ __launch_bounds__(256, 4) void vq_p2(
    const short* __restrict__ zF, const short* __restrict__ chA,
    const short* __restrict__ clA, const float* __restrict__ cn2f,
    const float* __restrict__ ctA, float* __restrict__ susum) {
  const int lane = threadIdx.x & 63;
  const int wv = threadIdx.x >> 6;
  const int b = blockIdx.x;
  // XCD swizzle: all 8 blocks of one point-group on one XCD (L2 reuse)
  const int xcd = b & 7;
  const int sl = b >> 3;                 // 0..127
  const int pg = xcd * 16 + (sl >> 3);   // 0..127 point group (1024 points)
  const int g = (sl & 7) * 4 + wv;       // 0..31 code tile
  const int col = lane & 31;
  const int hf = lane >> 5;

  // resident codebook B frags, negated (codebook is +c*log2e; we need -c)
  bf16x8 Bh[4], Bl[4];
  const short* ch = chA + ((size_t)(g * 4) * 64 + lane) * 8;
  const short* cl = clA + ((size_t)(g * 4) * 64 + lane) * 8;
#pragma unroll
  for (int ks = 0; ks < 4; ks++) {
    Bh[ks] = negbf8(*(const bf16x8*)(ch + ks * 512));
    Bl[ks] = negbf8(*(const bf16x8*)(cl + ks * 512));
  }
  const float cnv = cn2f[g * 32 + col];  // this lane's code norm (scaled)

  float su = 0.0f;
  for (int pt = 0; pt < 32; pt++) {
    const int T = pg * 32 + pt;
    const short* base = zF + (size_t)T * 4096;
    float4 ctv[4];
#pragma unroll
    for (int q = 0; q < 4; q++)
      ctv[q] = *(const float4*)(ctA + T * 32 + 8 * q + 4 * hf);
    f32x16 acc0, acc1;
#pragma unroll
    for (int r = 0; r < 16; r++) {
      acc0[r] = ((const float*)&ctv[r >> 2])[r & 3] - cnv;
      acc1[r] = 0.0f;
    }
#pragma unroll
    for (int ks = 0; ks < 4; ks++) {
      bf16x8 Ah = *(const bf16x8*)(base + (ks * 64 + lane) * 8);
      bf16x8 Al = *(const bf16x8*)(base + 2048 + (ks * 64 + lane) * 8);
      acc0 = __builtin_amdgcn_mfma_f32_32x32x16_bf16(Ah, Bh[ks], acc0, 0, 0, 0);
      acc1 = __builtin_amdgcn_mfma_f32_32x32x16_bf16(Ah, Bl[ks], acc1, 0, 0, 0);
      acc1 = __builtin_amdgcn_mfma_f32_32x32x16_bf16(Al, Bh[ks], acc1, 0, 0, 0);
    }
#pragma unroll
    for (int r = 0; r < 16; r++) su += exp2f(acc0[r] + acc1[r]);
  }
  su += __shfl_xor(su, 32, 64);
  if (hf == 0) atomicAdd(&susum[g * 32 + col], su);
}

// ---------------------------------------------------------------------------
// Epilogue: wave per point. Exact fp32 rescan for small-margin points,
// then quantized_st / counts / indices / sqerr.
__global__ __launch_bounds__(256) void vq_epi(
    const float* __restrict__ z, const float* __restrict__ cb,
    const float* __restrict__ cn, float* __restrict__ out,
    const float* __restrict__ mgA, float* __restrict__ counts,
    float* __restrict__ sqp) {
  __shared__ float red[4];
  const int wv = threadIdx.x >> 6;
  const int i = blockIdx.x * 4 + wv;
  const int lane = threadIdx.x & 63;
  float* slot = out + O_QST + (size_t)i * 64;
  int bI = (int)out[O_IDX + (size_t)i];
  const float margin = mgA[i];  // wave-uniform

  if (margin < DELTA) {
    const float4* zi4 = (const float4*)(z + (size_t)i * 64);
    float4 zq[16];
#pragma unroll
    for (int k = 0; k < 16; k++) zq[k] = zi4[k];
    float best = 3.0e38f;
    int bidx = 0;
    for (int cc = 0; cc < 16; cc++) {
      int c = cc * 64 + lane;
      const float4* cr = (const float4*)(cb + (size_t)c * 64);
      float dot0 = 0.0f, dot1 = 0.0f;
#pragma unroll
      for (int k = 0; k < 16; k += 2) {
        float4 a = cr[k];
        float4 bq = cr[k + 1];
        dot0 += zq[k].x * a.x + zq[k].y * a.y + zq[k].z * a.z + zq[k].w * a.w;
        dot1 += zq[k + 1].x * bq.x + zq[k + 1].y * bq.y + zq[k + 1].z * bq.z +
                zq[k + 1].w * bq.w;
      }
      float s = cn[c] - 2.0f * (dot0 + dot1);
      if (s < best) { best = s; bidx = c; }
    }
#pragma unroll
    for (int o = 32; o > 0; o >>= 1) {
      float ob = __shfl_xor(best, o, 64);
      int oi = __shfl_xor(bidx, o, 64);
      if (ob < best || (ob == best && oi < bidx)) { best = ob; bidx = oi; }
    }
    bI = bidx;
    if (lane == 0) out[O_IDX + (size_t)i] = (float)bI;
  }

  float qv = cb[(size_t)bI * 64 + lane];
  float zv = z[(size_t)i * 64 + lane];
  float o = zv + (qv - zv);
  float e = qv - zv;
  float s = e * e;
#pragma unroll
  for (int off = 32; off > 0; off >>= 1) s += __shfl_xor(s, off, 64);
  slot[lane] = o;
  if (lane == 0) {
    atomicAdd(&counts[bI], 1.0f);
    red[wv] = s;
  }
  __syncthreads();
  if (threadIdx.x == 0) {
    float v = red[0] + red[1] + red[2] + red[3];
    atomicAdd(&sqp[blockIdx.x & 255], v);
  }
}

// ---------------------------------------------------------------------------
__global__ __launch_bounds__(1024) void vq_final(
    const float* __restrict__ counts, const float* __restrict__ susum,
    const float* __restrict__ sqp, float* __restrict__ out) {
  __shared__ float red[16];
  __shared__ float red2[16];
  const int t = threadIdx.x;
  float cnt = counts[t];
  float usage = cnt * INV_N;
  out[O_USG + t] = usage;
  out[O_SU + t] = susum[t] * INV_N;
  float term = usage * logf(usage + 1e-8f);
  float sq = (t < 256) ? sqp[t] : 0.0f;
#pragma unroll
  for (int o = 32; o > 0; o >>= 1) {
    term += __shfl_xor(term, o, 64);
    sq += __shfl_xor(sq, o, 64);
  }
  if ((t & 63) == 0) {
    red[t >> 6] = term;
    red2[t >> 6] = sq;
  }
  __syncthreads();
  if (t < 16) {
    float v = red[t];
    float s2 = red2[t];
#pragma unroll
    for (int o = 8; o > 0; o >>= 1) {
      v += __shfl_xor(v, o, 64);
      s2 += __shfl_xor(s2, o, 64);
    }
    if (t == 0) {
      float ppl = __expf(-v);
      float cbl = s2 * INV_ELEMS;
      out[O_LOSS] = cbl + 0.25f * cbl;
      out[O_CBL] = cbl;
      out[O_CML] = cbl;
      out[O_PPL] = ppl;
    }
  }
}

// ---------------------------------------------------------------------------
extern "C" void kernel_launch(void* const* d_in, const int* in_sizes, int n_in,
                              void* d_out, int out_size, void* d_ws,
                              size_t ws_size, hipStream_t stream) {
  const float* z = (const float*)d_in[0];
  const float* cb = (const float*)d_in[1];
  float* ws = (float*)d_ws;
  float* cn = ws;
  float* counts = ws + 1024;
  float* susum = ws + 2048;
  float* sqp = ws + 3072;
  float* cn2f = ws + 3328;
  short* chA = (short*)(ws + 4352);
  short* clA = (short*)(ws + 37120);
  float* ctA = ws + 69888;
  float* mgA = ws + 200960;
  float* out = (float*)d_out;

  hipMemsetAsync(counts, 0, (1024 + 1024 + 256) * sizeof(float), stream);

  vq_norms<<<K, 64, 0, stream>>>(cb, cn);
  vq_prep<<<256, 256, 0, stream>>>(cb, cn, chA, clA, cn2f);
  vq_p1<<<1024, 256, 0, stream>>>(z, chA, clA, cn2f, out, ctA, mgA);
  vq_p2<<<1024, 256, 0, stream>>>((const short*)out, chA, clA, cn2f, ctA,
                                  susum);
  vq_epi<<<N / 4, 256, 0, stream>>>(z, cb, cn, out, mgA, counts, sqp);
  vq_final<<<1, 1024, 0, stream>>>(counts, susum, sqp, out);
}